// Round 7
// baseline (142.439 us; speedup 1.0000x reference)
//
#include <hip/hip_runtime.h>
#include <cstdint>
#include <cmath>

#define Bb   128
#define INN  1024
#define OUTN 1024
#define A_TOT   (0.005f / 128.0f)   // fold mean-over-B (exact /2^7) into amplitude
#define INV_TAU (1.0f / 20.0f)

// round-to-nearest-even f32 -> bf16 (as uint16 in low bits)
__device__ __forceinline__ uint32_t rne_bf16(float f) {
    uint32_t u = __float_as_uint(f);
    return (u + 0x7fffu + ((u >> 16) & 1u)) >> 16;
}

// ---------------------------------------------------------------------------
// 1) prep: W transpose + IPack + spike compaction + out_W = W seed copy.
//    512 blocks x 256. The seed copy lets stdp_k accumulate straight into
//    out_W with f32 atomics (stream-ordered after this kernel).
//    IPackB[b,i] = (bf16(Iz)<<16) | bf16(Iy), Iz=e^{-dp/tau}, Iy=A*e^{dp/tau}
// ---------------------------------------------------------------------------
__global__ __launch_bounds__(256) void prep_k(
    const float* __restrict__ W, const float* __restrict__ in_spikes,
    const float* __restrict__ delta_pre,
    float* __restrict__ Wt, uint32_t* __restrict__ IPackB,
    int* __restrict__ gIdx, int* __restrict__ gCount,
    float* __restrict__ out_W) {
    __shared__ float tile[32][33];
    const int blk = blockIdx.x;           // 0..511
    const int t   = threadIdx.x;

    // seed copy: out_W = W (512 float4 per block)
    {
        const size_t base = (size_t)blk * 512 + t;
        ((float4*)out_W)[base]       = ((const float4*)W)[base];
        ((float4*)out_W)[base + 256] = ((const float4*)W)[base + 256];
    }

    // spike compaction (ballot order: deterministic across replays)
    if ((blk & 3) == 0 && t < 64) {
        const int b = blk >> 2;
        int base = 0;
#pragma unroll
        for (int c = 0; c < 16; c++) {
            float s = in_spikes[(size_t)b * INN + c * 64 + t];
            unsigned long long m = __ballot(s > 0.0f);
            if (s > 0.0f) {
                int pos = base + __popcll(m & ((1ULL << t) - 1ULL));
                gIdx[b * INN + pos] = c * 64 + t;
            }
            base += __popcll(m);
        }
        if (t == 0) gCount[b] = base;
    }

    // IPack: one (b,i) entry per thread
    {
        const int e = blk * 256 + t;      // 0..131071
        float sp = in_spikes[e];
        float dp = (sp > 0.0f) ? 0.0f : delta_pre[e] + 1.0f;
        float Iz = expf(-dp * INV_TAU);
        float Iy = A_TOT * expf(dp * INV_TAU);
        IPackB[e] = (rne_bf16(Iz) << 16) | rne_bf16(Iy);
    }

    // transpose: two 32x32 tiles per block
    const int x = t & 31, y = t >> 5;
#pragma unroll
    for (int k = 0; k < 2; k++) {
        int tau = blk * 2 + k;
        int bx = tau & 31, by = tau >> 5;     // bx: i-tile, by: o-tile
        __syncthreads();
#pragma unroll
        for (int j = 0; j < 4; j++)
            tile[y + j * 8][x] = W[(size_t)(by * 32 + y + j * 8) * INN + bx * 32 + x];
        __syncthreads();
#pragma unroll
        for (int j = 0; j < 4; j++)
            Wt[(size_t)(bx * 32 + y + j * 8) * OUTN + by * 32 + x] = tile[x][y + j * 8];
    }
}

// ---------------------------------------------------------------------------
// 2) sparse projection + LIF + OPack. grid (B,4), block (b,z) covers
//    o = z*256+t. Index list precomputed by prep_k.
//    OPackB[b,o] = (bf16(Oy)<<16) | bf16(Oz), Oy=e^{-df/tau}, Oz=-A*e^{df/tau}
// ---------------------------------------------------------------------------
__global__ __launch_bounds__(256) void spmv_lif_k(
    const float* __restrict__ Wt, const float* __restrict__ membrane,
    const float* __restrict__ delta_fire,
    const int* __restrict__ gIdx, const int* __restrict__ gCount,
    uint32_t* __restrict__ OPackB,
    float* __restrict__ out_spike, float* __restrict__ out_mem) {
    __shared__ int sIdx[INN];
    const int b = blockIdx.x;
    const int z = blockIdx.y;
    const int t = threadIdx.x;
    const int n = gCount[b];
    for (int j = t; j < n; j += 256) sIdx[j] = gIdx[b * INN + j];
    __syncthreads();

    const int o = z * 256 + t;
    float acc = 0.0f;
    int j = 0;
    for (; j + 8 <= n; j += 8) {            // 8 loads in flight
        float w0 = Wt[(size_t)sIdx[j + 0] * OUTN + o];
        float w1 = Wt[(size_t)sIdx[j + 1] * OUTN + o];
        float w2 = Wt[(size_t)sIdx[j + 2] * OUTN + o];
        float w3 = Wt[(size_t)sIdx[j + 3] * OUTN + o];
        float w4 = Wt[(size_t)sIdx[j + 4] * OUTN + o];
        float w5 = Wt[(size_t)sIdx[j + 5] * OUTN + o];
        float w6 = Wt[(size_t)sIdx[j + 6] * OUTN + o];
        float w7 = Wt[(size_t)sIdx[j + 7] * OUTN + o];
        acc += ((w0 + w1) + (w2 + w3)) + ((w4 + w5) + (w6 + w7));
    }
    for (; j < n; j++) acc += Wt[(size_t)sIdx[j] * OUTN + o];

    const int n_bo = b * OUTN + o;
    float mem = membrane[n_bo] * 0.99f + acc;
    float s = (mem > 1.0f) ? 1.0f : 0.0f;
    mem = (s > 0.0f) ? mem - 0.8f : mem;
    out_spike[n_bo] = s;
    out_mem[n_bo] = mem;

    float df = (s > 0.0f) ? 0.0f : delta_fire[n_bo] + 1.0f;
    float Oy = expf(-df * INV_TAU);
    float Oz = -A_TOT * expf(df * INV_TAU);
    OPackB[n_bo] = (rne_bf16(Oy) << 16) | rne_bf16(Oz);
}

// ---------------------------------------------------------------------------
// 3) STDP: out_W[o,i] += sum_b sel(df>dp: Oy*Iy, df<dp: Oz*Iz)
//      min_u32(pO,pI) = selected key, max_u32(pO,pI)<<16 = selected payload.
//    64x64 tile, 4x4 micro-tile (2 x ds_read_b128 per 16 products), B split
//    across 4 blocks (32 b's each, single barrier pair). Grid (256,4) = 1024
//    blocks -> 4 blocks/CU, 16 waves/CU. Epilogue: f32 atomics into out_W
//    (seeded with W by prep_k; distinct addrs, 4-way sharing; reorder noise
//    ~1e-8 << threshold).
// ---------------------------------------------------------------------------
__global__ __launch_bounds__(256, 4) void stdp_k(
    const uint32_t* __restrict__ OPackB, const uint32_t* __restrict__ IPackB,
    float* __restrict__ out_W) {
    __shared__ uint32_t sO[32][64];   // 8 KB
    __shared__ uint32_t sI[32][64];   // 8 KB
    const int t    = threadIdx.x;
    const int tile = blockIdx.x;            // 256 tiles
    const int b0   = blockIdx.y * 32;       // B quarter
    const int o0 = (tile & 15) * 64, i0 = (tile >> 4) * 64;
    const int tx = t & 15, ty = t >> 4;     // i=i0+4tx+c, o=o0+4ty+a

#pragma unroll
    for (int r = 0; r < 2; r++) {           // stage 32 rows x 64 dwords each
        const int idx = r * 256 + t;
        const int row = idx >> 4, col = (idx & 15) * 4;
        *(uint4*)&sO[row][col] =
            *(const uint4*)&OPackB[(size_t)(b0 + row) * OUTN + o0 + col];
        *(uint4*)&sI[row][col] =
            *(const uint4*)&IPackB[(size_t)(b0 + row) * INN + i0 + col];
    }
    __syncthreads();

    float acc[4][4] = {{0.f}, {0.f}, {0.f}, {0.f}};
#pragma unroll
    for (int bb = 0; bb < 32; bb++) {
        uint4 po = *(const uint4*)&sO[bb][4 * ty];  // b128, broadcast over tx
        uint4 pi = *(const uint4*)&sI[bb][4 * tx];  // b128, 2-way bank alias
        const uint32_t ov[4] = {po.x, po.y, po.z, po.w};
        const uint32_t iv[4] = {pi.x, pi.y, pi.z, pi.w};
#pragma unroll
        for (int a = 0; a < 4; a++)
#pragma unroll
            for (int c = 0; c < 4; c++) {
                uint32_t key = min(ov[a], iv[c]);
                uint32_t pay = max(ov[a], iv[c]) << 16;
                acc[a][c] = fmaf(__uint_as_float(key),
                                 __uint_as_float(pay), acc[a][c]);
            }
    }

    // accumulate into out_W (seeded = W by prep_k)
#pragma unroll
    for (int a = 0; a < 4; a++) {
        float* dst = &out_W[(size_t)(o0 + 4 * ty + a) * INN + i0 + 4 * tx];
#pragma unroll
        for (int c = 0; c < 4; c++) atomicAdd(dst + c, acc[a][c]);
    }
}

// ---------------------------------------------------------------------------
extern "C" void kernel_launch(void* const* d_in, const int* in_sizes, int n_in,
                              void* d_out, int out_size, void* d_ws, size_t ws_size,
                              hipStream_t stream) {
    const float* in_spikes  = (const float*)d_in[0];
    const float* W          = (const float*)d_in[1];
    const float* membrane   = (const float*)d_in[2];
    const float* delta_pre  = (const float*)d_in[3];
    const float* delta_fire = (const float*)d_in[4];

    float* out_spike = (float*)d_out;                       // (B,OUT)
    float* out_W     = out_spike + (size_t)Bb * OUTN;       // (OUT,IN)
    float* out_mem   = out_W + (size_t)OUTN * INN;          // (B,OUT)

    float* ws        = (float*)d_ws;
    float* Wt        = ws;                                      // 4 MB
    uint32_t* OPackB = (uint32_t*)(Wt + (size_t)INN * OUTN);    // 512 KB
    uint32_t* IPackB = OPackB + (size_t)Bb * OUTN;              // 512 KB
    int* gIdx        = (int*)(IPackB + (size_t)Bb * INN);       // 512 KB
    int* gCount      = gIdx + (size_t)Bb * INN;                 // 512 B

    hipLaunchKernelGGL(prep_k, dim3(512), dim3(256), 0, stream,
                       W, in_spikes, delta_pre, Wt, IPackB, gIdx, gCount, out_W);
    hipLaunchKernelGGL(spmv_lif_k, dim3(Bb, 4), dim3(256), 0, stream,
                       Wt, membrane, delta_fire, gIdx, gCount,
                       OPackB, out_spike, out_mem);
    hipLaunchKernelGGL(stdp_k, dim3(256, 4), dim3(256), 0, stream,
                       OPackB, IPackB, out_W);
}

// Round 8
// 102.009 us; speedup vs baseline: 1.3963x; 1.3963x over previous
//
#include <hip/hip_runtime.h>
#include <cstdint>
#include <cmath>

#define Bb   128
#define INN  1024
#define OUTN 1024
#define A_TOT   (0.005f / 128.0f)   // fold mean-over-B (exact /2^7) into amplitude
#define INV_TAU (1.0f / 20.0f)

// round-to-nearest-even f32 -> bf16 (as uint16 in low bits)
__device__ __forceinline__ uint32_t rne_bf16(float f) {
    uint32_t u = __float_as_uint(f);
    return (u + 0x7fffu + ((u >> 16) & 1u)) >> 16;
}

// ---------------------------------------------------------------------------
// 1) prep: W transpose + IPack + spike compaction (round-5 proven).
//    IPackB[b,i] = (bf16(Iz)<<16) | bf16(Iy), Iz=e^{-dp/tau}, Iy=A*e^{dp/tau}
// ---------------------------------------------------------------------------
__global__ __launch_bounds__(256) void prep_k(
    const float* __restrict__ W, const float* __restrict__ in_spikes,
    const float* __restrict__ delta_pre,
    float* __restrict__ Wt, uint32_t* __restrict__ IPackB,
    int* __restrict__ gIdx, int* __restrict__ gCount) {
    __shared__ float tile[32][33];
    const int blk = blockIdx.x;           // 0..511
    const int t   = threadIdx.x;

    // spike compaction (ballot order: deterministic across replays)
    if ((blk & 3) == 0 && t < 64) {
        const int b = blk >> 2;
        int base = 0;
#pragma unroll
        for (int c = 0; c < 16; c++) {
            float s = in_spikes[(size_t)b * INN + c * 64 + t];
            unsigned long long m = __ballot(s > 0.0f);
            if (s > 0.0f) {
                int pos = base + __popcll(m & ((1ULL << t) - 1ULL));
                gIdx[b * INN + pos] = c * 64 + t;
            }
            base += __popcll(m);
        }
        if (t == 0) gCount[b] = base;
    }

    // IPack: one (b,i) entry per thread
    {
        const int e = blk * 256 + t;      // 0..131071
        float sp = in_spikes[e];
        float dp = (sp > 0.0f) ? 0.0f : delta_pre[e] + 1.0f;
        float Iz = expf(-dp * INV_TAU);
        float Iy = A_TOT * expf(dp * INV_TAU);
        IPackB[e] = (rne_bf16(Iz) << 16) | rne_bf16(Iy);
    }

    // transpose: two 32x32 tiles per block
    const int x = t & 31, y = t >> 5;
#pragma unroll
    for (int k = 0; k < 2; k++) {
        int tau = blk * 2 + k;
        int bx = tau & 31, by = tau >> 5;     // bx: i-tile, by: o-tile
        __syncthreads();
#pragma unroll
        for (int j = 0; j < 4; j++)
            tile[y + j * 8][x] = W[(size_t)(by * 32 + y + j * 8) * INN + bx * 32 + x];
        __syncthreads();
#pragma unroll
        for (int j = 0; j < 4; j++)
            Wt[(size_t)(bx * 32 + y + j * 8) * OUTN + by * 32 + x] = tile[x][y + j * 8];
    }
}

// ---------------------------------------------------------------------------
// 2) sparse projection + LIF + OPack (o-major / transposed layout).
//    grid (B,4), block (b,z) covers o = z*256+t.
//    OPackT[o*B + b] = (bf16(Oy)<<16) | bf16(Oz), Oy=e^{-df/tau},
//    Oz=-A*e^{df/tau}. Scattered store (~0.2us) buys stdp_k b128 O-staging.
// ---------------------------------------------------------------------------
__global__ __launch_bounds__(256) void spmv_lif_k(
    const float* __restrict__ Wt, const float* __restrict__ membrane,
    const float* __restrict__ delta_fire,
    const int* __restrict__ gIdx, const int* __restrict__ gCount,
    uint32_t* __restrict__ OPackT,
    float* __restrict__ out_spike, float* __restrict__ out_mem) {
    __shared__ int sIdx[INN];
    const int b = blockIdx.x;
    const int z = blockIdx.y;
    const int t = threadIdx.x;
    const int n = gCount[b];
    for (int j = t; j < n; j += 256) sIdx[j] = gIdx[b * INN + j];
    __syncthreads();

    const int o = z * 256 + t;
    float acc = 0.0f;
    int j = 0;
    for (; j + 8 <= n; j += 8) {            // 8 loads in flight
        float w0 = Wt[(size_t)sIdx[j + 0] * OUTN + o];
        float w1 = Wt[(size_t)sIdx[j + 1] * OUTN + o];
        float w2 = Wt[(size_t)sIdx[j + 2] * OUTN + o];
        float w3 = Wt[(size_t)sIdx[j + 3] * OUTN + o];
        float w4 = Wt[(size_t)sIdx[j + 4] * OUTN + o];
        float w5 = Wt[(size_t)sIdx[j + 5] * OUTN + o];
        float w6 = Wt[(size_t)sIdx[j + 6] * OUTN + o];
        float w7 = Wt[(size_t)sIdx[j + 7] * OUTN + o];
        acc += ((w0 + w1) + (w2 + w3)) + ((w4 + w5) + (w6 + w7));
    }
    for (; j < n; j++) acc += Wt[(size_t)sIdx[j] * OUTN + o];

    const int n_bo = b * OUTN + o;
    float mem = membrane[n_bo] * 0.99f + acc;
    float s = (mem > 1.0f) ? 1.0f : 0.0f;
    mem = (s > 0.0f) ? mem - 0.8f : mem;
    out_spike[n_bo] = s;
    out_mem[n_bo] = mem;

    float df = (s > 0.0f) ? 0.0f : delta_fire[n_bo] + 1.0f;
    float Oy = expf(-df * INV_TAU);
    float Oz = -A_TOT * expf(df * INV_TAU);
    OPackT[(size_t)o * Bb + b] = (rne_bf16(Oy) << 16) | rne_bf16(Oz);
}

// ---------------------------------------------------------------------------
// 3) STDP: new_W[o,i] = W[o,i] + sum_b sel(df>dp: Oy*Iy, df<dp: Oz*Iz)
//      min_u32(pO,pI) = selected key, max_u32(pO,pI)<<16 = selected payload.
//    32(o) x 64(i) tile, 2x4 micro-tile. O staged TRANSPOSED sOT[o][bb]
//    (one b128 = 4 bb per o): per 4-bb step 6 x b128 = 72 cyc / 32 products
//    = 2.25 cyc/prod. XOR swizzle on bb-chunk (^(ty&7)) spreads the 16
//    lane-group addresses over all 32 banks -> 2-way max (free, m136);
//    stride-32 rows keep b128 16-B alignment. Grid (32,16)=512 blocks,
//    2 blocks/CU, 8 waves/CU, 12 KB LDS.
// ---------------------------------------------------------------------------
__global__ __launch_bounds__(256, 2) void stdp_k(
    const float* __restrict__ W, const uint32_t* __restrict__ OPackT,
    const uint32_t* __restrict__ IPackB, float* __restrict__ outW) {
    __shared__ uint32_t sOT[32 * 32];   // [o][bb^swz]  4 KB
    __shared__ uint32_t sI[32 * 64];    // [bb][i]      8 KB
    const int t  = threadIdx.x;
    const int o0 = blockIdx.x * 32;
    const int i0 = blockIdx.y * 64;
    const int tx = t & 15;              // i = i0 + 4*tx + c
    const int ty = t >> 4;              // o = o0 + 2*ty + a
    const int swz = ty & 7;

    float acc[2][4] = {{0.f, 0.f, 0.f, 0.f}, {0.f, 0.f, 0.f, 0.f}};

    for (int cb = 0; cb < Bb / 32; cb++) {         // 4 chunks of 32 b
        const int b0 = cb * 32;
        {   // stage sOT: 32 o-rows x 32 bb, bb-chunk XOR-swizzled by (o>>1)&7
            const int col = t & 31, rbase = t >> 5;    // rbase 0..7
#pragma unroll
            for (int r = 0; r < 4; r++) {
                const int orow = r * 8 + rbase;
                const uint32_t v = OPackT[(size_t)(o0 + orow) * Bb + b0 + col];
                sOT[orow * 32 + ((((col >> 2) ^ ((orow >> 1) & 7)) << 2) | (col & 3))] = v;
            }
        }
#pragma unroll
        for (int r = 0; r < 2; r++) {   // stage sI: 32 bb-rows x 64 i (b128)
            const int idx = r * 256 + t;
            const int row = idx >> 4, col = (idx & 15) * 4;
            *(uint4*)&sI[row * 64 + col] =
                *(const uint4*)&IPackB[(size_t)(b0 + row) * INN + i0 + col];
        }
        __syncthreads();

#pragma unroll
        for (int c4 = 0; c4 < 8; c4++) {           // 4 bb per step
            const int chunk = (c4 ^ swz) << 2;
            uint4 oA = *(const uint4*)&sOT[(2 * ty + 0) * 32 + chunk];
            uint4 oB = *(const uint4*)&sOT[(2 * ty + 1) * 32 + chunk];
            const uint32_t ovA[4] = {oA.x, oA.y, oA.z, oA.w};
            const uint32_t ovB[4] = {oB.x, oB.y, oB.z, oB.w};
#pragma unroll
            for (int k = 0; k < 4; k++) {          // bb = b0 + 4*c4 + k
                uint4 pi = *(const uint4*)&sI[(4 * c4 + k) * 64 + 4 * tx];
                const uint32_t iv[4] = {pi.x, pi.y, pi.z, pi.w};
#pragma unroll
                for (int c = 0; c < 4; c++) {
                    uint32_t k0 = min(ovA[k], iv[c]);
                    uint32_t p0 = max(ovA[k], iv[c]) << 16;
                    acc[0][c] = fmaf(__uint_as_float(k0),
                                     __uint_as_float(p0), acc[0][c]);
                    uint32_t k1 = min(ovB[k], iv[c]);
                    uint32_t p1 = max(ovB[k], iv[c]) << 16;
                    acc[1][c] = fmaf(__uint_as_float(k1),
                                     __uint_as_float(p1), acc[1][c]);
                }
            }
        }
        __syncthreads();
    }

    // epilogue: new_W = W + acc  (float4 per (o, 4*tx))
#pragma unroll
    for (int a = 0; a < 2; a++) {
        const size_t off = (size_t)(o0 + 2 * ty + a) * INN + i0 + 4 * tx;
        float4 w = *(const float4*)&W[off];
        *(float4*)&outW[off] = make_float4(w.x + acc[a][0], w.y + acc[a][1],
                                           w.z + acc[a][2], w.w + acc[a][3]);
    }
}

// ---------------------------------------------------------------------------
extern "C" void kernel_launch(void* const* d_in, const int* in_sizes, int n_in,
                              void* d_out, int out_size, void* d_ws, size_t ws_size,
                              hipStream_t stream) {
    const float* in_spikes  = (const float*)d_in[0];
    const float* W          = (const float*)d_in[1];
    const float* membrane   = (const float*)d_in[2];
    const float* delta_pre  = (const float*)d_in[3];
    const float* delta_fire = (const float*)d_in[4];

    float* out_spike = (float*)d_out;                       // (B,OUT)
    float* out_W     = out_spike + (size_t)Bb * OUTN;       // (OUT,IN)
    float* out_mem   = out_W + (size_t)OUTN * INN;          // (B,OUT)

    float* ws        = (float*)d_ws;
    float* Wt        = ws;                                      // 4 MB
    uint32_t* OPackT = (uint32_t*)(Wt + (size_t)INN * OUTN);    // 512 KB
    uint32_t* IPackB = OPackT + (size_t)OUTN * Bb;              // 512 KB
    int* gIdx        = (int*)(IPackB + (size_t)Bb * INN);       // 512 KB
    int* gCount      = gIdx + (size_t)Bb * INN;                 // 512 B

    hipLaunchKernelGGL(prep_k, dim3(512), dim3(256), 0, stream,
                       W, in_spikes, delta_pre, Wt, IPackB, gIdx, gCount);
    hipLaunchKernelGGL(spmv_lif_k, dim3(Bb, 4), dim3(256), 0, stream,
                       Wt, membrane, delta_fire, gIdx, gCount,
                       OPackT, out_spike, out_mem);
    hipLaunchKernelGGL(stdp_k, dim3(OUTN / 32, INN / 64), dim3(256), 0, stream,
                       W, OPackT, IPackB, out_W);
}

// Round 9
// 99.798 us; speedup vs baseline: 1.4273x; 1.0222x over previous
//
#include <hip/hip_runtime.h>
#include <cstdint>
#include <cmath>

#define Bb   128
#define INN  1024
#define OUTN 1024
#define A_TOT   (0.005f / 128.0f)   // fold mean-over-B (exact /2^7) into amplitude
#define INV_TAU (1.0f / 20.0f)

// round-to-nearest-even f32 -> bf16 (as uint16 in low bits)
__device__ __forceinline__ uint32_t rne_bf16(float f) {
    uint32_t u = __float_as_uint(f);
    return (u + 0x7fffu + ((u >> 16) & 1u)) >> 16;
}

// ---------------------------------------------------------------------------
// 1) prep: W transpose + IPackT + spike compaction.
//    IPackT[i*B + b] = (bf16(Iz)<<16) | bf16(Iy), Iz=e^{-dp/tau},
//    Iy=A*e^{dp/tau}.  b-minor layout so stdp stages it b128-wise.
// ---------------------------------------------------------------------------
__global__ __launch_bounds__(256) void prep_k(
    const float* __restrict__ W, const float* __restrict__ in_spikes,
    const float* __restrict__ delta_pre,
    float* __restrict__ Wt, uint32_t* __restrict__ IPackT,
    int* __restrict__ gIdx, int* __restrict__ gCount) {
    __shared__ float tile[32][33];
    const int blk = blockIdx.x;           // 0..511
    const int t   = threadIdx.x;

    // spike compaction (ballot order: deterministic across replays)
    if ((blk & 3) == 0 && t < 64) {
        const int b = blk >> 2;
        int base = 0;
#pragma unroll
        for (int c = 0; c < 16; c++) {
            float s = in_spikes[(size_t)b * INN + c * 64 + t];
            unsigned long long m = __ballot(s > 0.0f);
            if (s > 0.0f) {
                int pos = base + __popcll(m & ((1ULL << t) - 1ULL));
                gIdx[b * INN + pos] = c * 64 + t;
            }
            base += __popcll(m);
        }
        if (t == 0) gCount[b] = base;
    }

    // IPackT: one (b,i) entry per thread; coalesced read, scattered store
    {
        const int e = blk * 256 + t;      // 0..131071
        const int b = e >> 10, i = e & 1023;
        float sp = in_spikes[e];
        float dp = (sp > 0.0f) ? 0.0f : delta_pre[e] + 1.0f;
        float Iz = expf(-dp * INV_TAU);
        float Iy = A_TOT * expf(dp * INV_TAU);
        IPackT[(size_t)i * Bb + b] = (rne_bf16(Iz) << 16) | rne_bf16(Iy);
    }

    // transpose: two 32x32 tiles per block
    const int x = t & 31, y = t >> 5;
#pragma unroll
    for (int k = 0; k < 2; k++) {
        int tau = blk * 2 + k;
        int bx = tau & 31, by = tau >> 5;     // bx: i-tile, by: o-tile
        __syncthreads();
#pragma unroll
        for (int j = 0; j < 4; j++)
            tile[y + j * 8][x] = W[(size_t)(by * 32 + y + j * 8) * INN + bx * 32 + x];
        __syncthreads();
#pragma unroll
        for (int j = 0; j < 4; j++)
            Wt[(size_t)(bx * 32 + y + j * 8) * OUTN + by * 32 + x] = tile[x][y + j * 8];
    }
}

// ---------------------------------------------------------------------------
// 2) sparse projection + LIF + OPackT (b-minor). grid (B,4), block (b,z)
//    covers o = z*256+t.
//    OPackT[o*B + b] = (bf16(Oy)<<16) | bf16(Oz), Oy=e^{-df/tau},
//    Oz=-A*e^{df/tau}.
// ---------------------------------------------------------------------------
__global__ __launch_bounds__(256) void spmv_lif_k(
    const float* __restrict__ Wt, const float* __restrict__ membrane,
    const float* __restrict__ delta_fire,
    const int* __restrict__ gIdx, const int* __restrict__ gCount,
    uint32_t* __restrict__ OPackT,
    float* __restrict__ out_spike, float* __restrict__ out_mem) {
    __shared__ int sIdx[INN];
    const int b = blockIdx.x;
    const int z = blockIdx.y;
    const int t = threadIdx.x;
    const int n = gCount[b];
    for (int j = t; j < n; j += 256) sIdx[j] = gIdx[b * INN + j];
    __syncthreads();

    const int o = z * 256 + t;
    float acc = 0.0f;
    int j = 0;
    for (; j + 8 <= n; j += 8) {            // 8 loads in flight
        float w0 = Wt[(size_t)sIdx[j + 0] * OUTN + o];
        float w1 = Wt[(size_t)sIdx[j + 1] * OUTN + o];
        float w2 = Wt[(size_t)sIdx[j + 2] * OUTN + o];
        float w3 = Wt[(size_t)sIdx[j + 3] * OUTN + o];
        float w4 = Wt[(size_t)sIdx[j + 4] * OUTN + o];
        float w5 = Wt[(size_t)sIdx[j + 5] * OUTN + o];
        float w6 = Wt[(size_t)sIdx[j + 6] * OUTN + o];
        float w7 = Wt[(size_t)sIdx[j + 7] * OUTN + o];
        acc += ((w0 + w1) + (w2 + w3)) + ((w4 + w5) + (w6 + w7));
    }
    for (; j < n; j++) acc += Wt[(size_t)sIdx[j] * OUTN + o];

    const int n_bo = b * OUTN + o;
    float mem = membrane[n_bo] * 0.99f + acc;
    float s = (mem > 1.0f) ? 1.0f : 0.0f;
    mem = (s > 0.0f) ? mem - 0.8f : mem;
    out_spike[n_bo] = s;
    out_mem[n_bo] = mem;

    float df = (s > 0.0f) ? 0.0f : delta_fire[n_bo] + 1.0f;
    float Oy = expf(-df * INV_TAU);
    float Oz = -A_TOT * expf(df * INV_TAU);
    OPackT[(size_t)o * Bb + b] = (rne_bf16(Oy) << 16) | rne_bf16(Oz);
}

// ---------------------------------------------------------------------------
// 3) STDP: new_W[o,i] = W[o,i] + sum_b sel(df>dp: Oy*Iy, df<dp: Oz*Iz)
//      min_u32(pO,pI) = selected key, max_u32(pO,pI)<<16 = selected payload.
//    32x32 tile, 2x2 micro, BOTH operands staged b-minor (sOT[o][b],
//    sIT[i][b]): per 4-b step 4 x b128 = 48 cyc / 16 products = 3.0
//    cyc/prod at 16 waves/CU (grid (32,32)=1024 blocks, 4 blk/CU — the
//    occupancy point R4 showed runs at ~90% of LDS floor). XOR swizzle
//    (chunk ^ ((row>>1)&7)) keeps staging a bank permutation and reads
//    <=2-way aliased (free, m136) while preserving 16-B alignment.
// ---------------------------------------------------------------------------
__global__ __launch_bounds__(256, 4) void stdp_k(
    const float* __restrict__ W, const uint32_t* __restrict__ OPackT,
    const uint32_t* __restrict__ IPackT, float* __restrict__ outW) {
    __shared__ uint32_t sOT[32 * 32];   // [o][b-chunk swz]  4 KB
    __shared__ uint32_t sIT[32 * 32];   // [i][b-chunk swz]  4 KB
    const int t  = threadIdx.x;
    const int o0 = blockIdx.x * 32;
    const int i0 = blockIdx.y * 32;
    const int tx = t & 15;              // i = i0 + 2*tx + {0,1}
    const int ty = t >> 4;              // o = o0 + 2*ty + {0,1}
    const int srow = t >> 3;            // staging row 0..31
    const int sc   = t & 7;             // staging b-chunk 0..7
    const int swr  = (srow >> 1) & 7;   // row swizzle key
    const int so = ty & 7, si = tx & 7; // read swizzle keys

    float acc[2][2] = {{0.f, 0.f}, {0.f, 0.f}};

    for (int cb = 0; cb < Bb / 32; cb++) {         // 4 chunks of 32 b
        const int b0 = cb * 32;
        // stage: one uint4 (4 b's) per array per thread, bank-permuted cols
        *(uint4*)&sOT[srow * 32 + ((sc ^ swr) << 2)] =
            *(const uint4*)&OPackT[(size_t)(o0 + srow) * Bb + b0 + 4 * sc];
        *(uint4*)&sIT[srow * 32 + ((sc ^ swr) << 2)] =
            *(const uint4*)&IPackT[(size_t)(i0 + srow) * Bb + b0 + 4 * sc];
        __syncthreads();

#pragma unroll
        for (int c4 = 0; c4 < 8; c4++) {           // 4 b's per step
            const int co = (c4 ^ so) << 2;
            const int ci = (c4 ^ si) << 2;
            uint4 oA = *(const uint4*)&sOT[(2 * ty + 0) * 32 + co];
            uint4 oB = *(const uint4*)&sOT[(2 * ty + 1) * 32 + co];
            uint4 iA = *(const uint4*)&sIT[(2 * tx + 0) * 32 + ci];
            uint4 iB = *(const uint4*)&sIT[(2 * tx + 1) * 32 + ci];
            const uint32_t ovA[4] = {oA.x, oA.y, oA.z, oA.w};
            const uint32_t ovB[4] = {oB.x, oB.y, oB.z, oB.w};
            const uint32_t ivA[4] = {iA.x, iA.y, iA.z, iA.w};
            const uint32_t ivB[4] = {iB.x, iB.y, iB.z, iB.w};
#pragma unroll
            for (int k = 0; k < 4; k++) {          // bb = b0 + 4*c4 + k
                uint32_t k00 = min(ovA[k], ivA[k]);
                uint32_t p00 = max(ovA[k], ivA[k]) << 16;
                acc[0][0] = fmaf(__uint_as_float(k00), __uint_as_float(p00),
                                 acc[0][0]);
                uint32_t k01 = min(ovA[k], ivB[k]);
                uint32_t p01 = max(ovA[k], ivB[k]) << 16;
                acc[0][1] = fmaf(__uint_as_float(k01), __uint_as_float(p01),
                                 acc[0][1]);
                uint32_t k10 = min(ovB[k], ivA[k]);
                uint32_t p10 = max(ovB[k], ivA[k]) << 16;
                acc[1][0] = fmaf(__uint_as_float(k10), __uint_as_float(p10),
                                 acc[1][0]);
                uint32_t k11 = min(ovB[k], ivB[k]);
                uint32_t p11 = max(ovB[k], ivB[k]) << 16;
                acc[1][1] = fmaf(__uint_as_float(k11), __uint_as_float(p11),
                                 acc[1][1]);
            }
        }
        __syncthreads();
    }

    // epilogue: new_W = W + acc  (float2 per (o, 2*tx))
#pragma unroll
    for (int a = 0; a < 2; a++) {
        const size_t off = (size_t)(o0 + 2 * ty + a) * INN + i0 + 2 * tx;
        float2 w = *(const float2*)&W[off];
        *(float2*)&outW[off] = make_float2(w.x + acc[a][0], w.y + acc[a][1]);
    }
}

// ---------------------------------------------------------------------------
extern "C" void kernel_launch(void* const* d_in, const int* in_sizes, int n_in,
                              void* d_out, int out_size, void* d_ws, size_t ws_size,
                              hipStream_t stream) {
    const float* in_spikes  = (const float*)d_in[0];
    const float* W          = (const float*)d_in[1];
    const float* membrane   = (const float*)d_in[2];
    const float* delta_pre  = (const float*)d_in[3];
    const float* delta_fire = (const float*)d_in[4];

    float* out_spike = (float*)d_out;                       // (B,OUT)
    float* out_W     = out_spike + (size_t)Bb * OUTN;       // (OUT,IN)
    float* out_mem   = out_W + (size_t)OUTN * INN;          // (B,OUT)

    float* ws        = (float*)d_ws;
    float* Wt        = ws;                                      // 4 MB
    uint32_t* OPackT = (uint32_t*)(Wt + (size_t)INN * OUTN);    // 512 KB
    uint32_t* IPackT = OPackT + (size_t)OUTN * Bb;              // 512 KB
    int* gIdx        = (int*)(IPackT + (size_t)INN * Bb);       // 512 KB
    int* gCount      = gIdx + (size_t)Bb * INN;                 // 512 B

    hipLaunchKernelGGL(prep_k, dim3(512), dim3(256), 0, stream,
                       W, in_spikes, delta_pre, Wt, IPackT, gIdx, gCount);
    hipLaunchKernelGGL(spmv_lif_k, dim3(Bb, 4), dim3(256), 0, stream,
                       Wt, membrane, delta_fire, gIdx, gCount,
                       OPackT, out_spike, out_mem);
    hipLaunchKernelGGL(stdp_k, dim3(OUTN / 32, INN / 32), dim3(256), 0, stream,
                       W, OPackT, IPackT, out_W);
}